// Round 14
// baseline (65.485 us; speedup 1.0000x reference)
//
#include <hip/hip_runtime.h>
#include <hip/hip_fp16.h>
#include <math.h>

#define BB 8
#define AA 1024
#define NN 64
#define FF 128
#define NG 25

#define WIDTH 0.2083333333f     /* 5/24 */
#define COEF  (-0.5f/(WIDTH*WIDTH))
#define PI_F  3.14159265358979f
#define CUTOFF 5.0f

#define KT 1024
#define HT (CUTOFF/(KT-1))
#define INVH ((float)(KT-1)/CUTOFF)
#define SENT ((unsigned)(KT-1))   /* sentinel code: T row = 0, j = 0 */

#define STR 132   /* LDS bf16 row stride (264 B) — verified conflict-free */

typedef __attribute__((ext_vector_type(8))) short bf16x8;
typedef __attribute__((ext_vector_type(4))) short bf16x4;
typedef __attribute__((ext_vector_type(4))) float f32x4;

__device__ __forceinline__ float sspf(float x){
    return fmaxf(x, 0.f) + log1pf(expf(-fabsf(x))) - 0.69314718056f;
}
__device__ __forceinline__ short bf16r(float x){
    union { float f; unsigned u; } v; v.f = x;
    unsigned r = v.u + 0x7FFF + ((v.u >> 16) & 1);
    return (short)(r >> 16);
}
__device__ __forceinline__ __half2 h2bc(unsigned u){
    union { unsigned u; __half2 h; } v; v.u = u; return v.h;
}

// ==== single prolog (unchanged from round 13, proven): codes+embed/in2f0
// (blocks 0..511), filter table (512..703), weight packing (704..959).
__global__ __launch_bounds__(512) void k_prep(const float* __restrict__ pos,
                        const float* __restrict__ cell,
                        const float* __restrict__ coff, const int* __restrict__ nbr,
                        const float* __restrict__ mask,
                        const int* __restrict__ z, const float* __restrict__ emb,
                        const float* __restrict__ fw1, const float* __restrict__ fb1,
                        const float* __restrict__ fw2, const float* __restrict__ fb2,
                        const float* __restrict__ in2f, const float* __restrict__ f2w,
                        const float* __restrict__ dw,
                        unsigned* __restrict__ codes, int* __restrict__ cnt,
                        short* __restrict__ Wp,
                        __half* __restrict__ T, float* __restrict__ x,
                        __half* __restrict__ y){
    __shared__ __align__(16) char smem[NG*FF*4 + 16*28*4 + 16*STR*2];
    float* s_w1 = (float*)smem;                              // NG*FF
    float* s_g  = (float*)(smem + NG*FF*4);                  // 16*28
    short* s_a  = (short*)(smem + NG*FF*4 + 16*28*4);        // 16*STR
    __shared__ unsigned s_codeP[16*NN];
    __shared__ int s_cnt[16];

    int p = blockIdx.x;
    int tid = threadIdx.x, wv = tid >> 6, lane = tid & 63;
    int m = lane & 15, q = lane >> 4;
    int col = 16*wv + m;

    if(p < 512){
        // ---- FIRST + CODES: 16 atoms, XCD-swizzled (batch = p&7) ----
        int row0 = ((p & 7)*64 + (p >> 3))*16;
        if(tid < 16) s_cnt[tid] = 0;
        s_codeP[2*tid]   = SENT;             // sentinel-fill all 1024 slots
        s_codeP[2*tid+1] = SENT;
        __syncthreads();
        #pragma unroll
        for(int u = 0; u < 2; u++){
            int pr = 2*tid + u;              // 0..1023
            int rr = pr >> 6, n = pr & 63;
            int row = row0 + rr;             // b*A + a
            int b = row >> 10;
            int flat = row*NN + n;
            int j = nbr[flat];
            const float* pi = pos + (size_t)row*3;
            const float* pj = pos + (size_t)(b*AA + j)*3;
            const float* co = coff + (size_t)flat*3;
            const float* cl = cell + b*9;
            float ox = co[0]*cl[0] + co[1]*cl[3] + co[2]*cl[6];
            float oy = co[0]*cl[1] + co[1]*cl[4] + co[2]*cl[7];
            float oz = co[0]*cl[2] + co[1]*cl[5] + co[2]*cl[8];
            float vx = pj[0]-pi[0]+ox, vy = pj[1]-pi[1]+oy, vz = pj[2]-pi[2]+oz;
            float d2 = vx*vx + vy*vy + vz*vz;
            float mk = mask[flat];
            float r  = sqrtf(mk > 0.f ? d2 : 1.0f) * mk;
            if(mk > 0.f && r < CUTOFF){      // out-of-cutoff pairs contribute 0: skip
                int iv = (int)(r*INVH + 0.5f);
                if(iv > KT-1) iv = KT-1;
                int ps = atomicAdd(&s_cnt[rr], 1);
                s_codeP[rr*NN + ps] = (unsigned)iv | ((unsigned)j << 16);
            }
        }
        __syncthreads();
        *(uint2*)&codes[row0*NN + 2*tid] = *(uint2*)&s_codeP[2*tid];
        if(tid < 16) cnt[row0 + tid] = s_cnt[tid];

        // self-pack in2f[0] fragments from fp32
        bf16x8 wf[4];
        #pragma unroll
        for(int ks = 0; ks < 4; ks++)
            #pragma unroll
            for(int i = 0; i < 8; i++)
                wf[ks][i] = bf16r(in2f[(32*ks + 8*q + i)*FF + col]);
        for(int i = tid; i < 16*FF; i += 512){
            int rr = i >> 7, f = i & (FF-1);
            float v = emb[z[row0+rr]*FF + f];
            x[(row0+rr)*FF + f] = v;
            s_a[rr*STR + f] = bf16r(v);
        }
        __syncthreads();
        f32x4 acc = {0.f,0.f,0.f,0.f};
        #pragma unroll
        for(int ks = 0; ks < 4; ks++){
            const short* ap = s_a + m*STR + 32*ks + 8*q;
            bf16x4 lo = *(const bf16x4*)ap;
            bf16x4 hi = *(const bf16x4*)(ap + 4);
            bf16x8 af;
            af[0]=lo[0]; af[1]=lo[1]; af[2]=lo[2]; af[3]=lo[3];
            af[4]=hi[0]; af[5]=hi[1]; af[6]=hi[2]; af[7]=hi[3];
            acc = __builtin_amdgcn_mfma_f32_16x16x32_bf16(af, wf[ks], acc, 0, 0, 0);
        }
        #pragma unroll
        for(int j = 0; j < 4; j++)
            y[(row0 + 4*q + j)*FF + col] = __float2half(acc[j]);
    } else if(p < 704){
        // ---- TABLE: knots 16*kb..16*kb+15 of layer l (64 blocks/layer) ----
        int tb = p - 512;
        int l = tb >> 6;
        int kb = tb & 63;
        const float* w2s = fw2 + l*16384;
        bf16x8 wf[4];
        #pragma unroll
        for(int ks = 0; ks < 4; ks++)
            #pragma unroll
            for(int i = 0; i < 8; i++)
                wf[ks][i] = bf16r(w2s[(32*ks + 8*q + i)*FF + col]);

        for(int i = tid; i < NG*FF; i += 512) s_w1[i] = fw1[l*NG*FF + i];
        for(int i = tid; i < 16*NG; i += 512){
            int kn = i/25, g = i - 25*kn;
            float d = (16*kb + kn)*HT - g*WIDTH;
            s_g[kn*28 + g] = expf(COEF*d*d);
        }
        __syncthreads();
        {
            int f = tid & (FF-1), g4 = tid >> 7;
            float b1v = fb1[l*FF + f];
            #pragma unroll
            for(int i = 0; i < 4; i++){
                int kn = g4 + 4*i;
                float zz = b1v;
                for(int g = 0; g < NG; g++)
                    zz = fmaf(s_g[kn*28 + g], s_w1[g*FF + f], zz);
                s_a[kn*STR + f] = bf16r(sspf(zz));
            }
        }
        __syncthreads();
        float b2 = fb2[l*FF + col];
        f32x4 acc = {b2, b2, b2, b2};
        #pragma unroll
        for(int ks = 0; ks < 4; ks++){
            const short* ap = s_a + m*STR + 32*ks + 8*q;
            bf16x4 lo = *(const bf16x4*)ap;
            bf16x4 hi = *(const bf16x4*)(ap + 4);
            bf16x8 af;
            af[0]=lo[0]; af[1]=lo[1]; af[2]=lo[2]; af[3]=lo[3];
            af[4]=hi[0]; af[5]=hi[1]; af[6]=hi[2]; af[7]=hi[3];
            acc = __builtin_amdgcn_mfma_f32_16x16x32_bf16(af, wf[ks], acc, 0, 0, 0);
        }
        #pragma unroll
        for(int j = 0; j < 4; j++){
            int kn = 16*kb + 4*q + j;
            float r = kn*HT;
            float C = (r < CUTOFF) ? 0.5f*(cosf(r*(PI_F/CUTOFF)) + 1.0f) : 0.f;
            T[(l*KT + kn)*FF + col] = __float2half(acc[j]*C);
        }
    } else {
        // ---- PACK: ids 0..2 f2w[l]; 3..5 dw[l]; 6,7 in2f[1],in2f[2] ----
        int idx = (p - 704)*512 + tid;               // < 8*16384
        int id = idx >> 14, rem = idx & 16383;
        int ks = rem >> 12, nt = (rem >> 9) & 7, ln = (rem >> 3) & 63, i = rem & 7;
        int k = 32*ks + 8*(ln >> 4) + i;
        int f = 16*nt + (ln & 15);
        const float* src = (id < 3) ? f2w + id*16384
                         : (id < 6) ? dw  + (id-3)*16384
                                    : in2f + (id-5)*16384;
        Wp[idx] = bf16r(src[k*FF + f]);
    }
}

// ---- fused layer: 8 atoms / 256 threads / 4 waves (2 col-tiles per wave) ----
// MFMA uses 16-row tiles; A rows 8-15 are junk but row r of D depends only on
// row r of A, so junk stays in discarded D rows. q>=2 half skips final writes.
__global__ __launch_bounds__(256) void k_layerM(const unsigned* __restrict__ codes,
                                                const int* __restrict__ cnt,
                                                const __half* __restrict__ Tl,
                                                const __half* __restrict__ yin,
                                                const short* __restrict__ w1p,
                                                const float* __restrict__ f2b,
                                                const short* __restrict__ w2p,
                                                const float* __restrict__ db,
                                                const short* __restrict__ w3p,
                                                float* __restrict__ x,
                                                __half* __restrict__ ynext){
    __shared__ unsigned s_code[8*NN];
    __shared__ short s_a[16*STR];
    __shared__ short s_t[16*STR];

    int tid = threadIdx.x, wv = tid >> 6, lane = tid & 63;   // wv in 0..3
    int m = lane & 15, q = lane >> 4;
    int p = blockIdx.x;
    int b = p & 7;                            // XCD swizzle: batch = p&7
    int row0 = (b*128 + (p >> 3))*8;          // 8 atoms per block
    int col  = 16*wv + m;                     // column tile wv
    int col2 = col + 64;                      //  and tile wv+4

    float b1a = f2b[col], b1b = f2b[col2];
    float b2a = db[col],  b2b = db[col2];

    *(uint2*)&s_code[2*tid] = *(const uint2*)&codes[row0*NN + 2*tid];
    __syncthreads();

    // ---- conv: branchless sentinel-padded lists; quarter-wave = 1 neighbor ----
    int qf = lane >> 4, fl = lane & 15, f8 = 8*fl;
    const __half* yb = yin + ((size_t)b*AA << 7) + f8;
    const __half* tb = Tl + f8;
    int a0 = 2*wv, a1 = 2*wv + 1;             // atoms 0..7
    int c0 = cnt[row0 + a0], c1 = cnt[row0 + a1];
    int cm = c0 > c1 ? c0 : c1;
    int nmax = (cm + 3) >> 2;                 // wave-uniform
    __half2 hz = __float2half2_rn(0.f);
    __half2 pa[4] = {hz,hz,hz,hz}, pb[4] = {hz,hz,hz,hz};
    float ca[8] = {0,0,0,0,0,0,0,0}, cb[8] = {0,0,0,0,0,0,0,0};
    #pragma unroll 4
    for(int t = 0; t < nmax; t++){
        unsigned cda = s_code[a0*NN + 4*t + qf];
        unsigned cdb = s_code[a1*NN + 4*t + qf];
        uint4 tva = *(const uint4*)(tb + ((cda & 0xFFFFu) << 7));
        uint4 yva = *(const uint4*)(yb + ((size_t)(cda >> 16) << 7));
        uint4 tvb = *(const uint4*)(tb + ((cdb & 0xFFFFu) << 7));
        uint4 yvb = *(const uint4*)(yb + ((size_t)(cdb >> 16) << 7));
        pa[0] = __hfma2(h2bc(tva.x), h2bc(yva.x), pa[0]);
        pa[1] = __hfma2(h2bc(tva.y), h2bc(yva.y), pa[1]);
        pa[2] = __hfma2(h2bc(tva.z), h2bc(yva.z), pa[2]);
        pa[3] = __hfma2(h2bc(tva.w), h2bc(yva.w), pa[3]);
        pb[0] = __hfma2(h2bc(tvb.x), h2bc(yvb.x), pb[0]);
        pb[1] = __hfma2(h2bc(tvb.y), h2bc(yvb.y), pb[1]);
        pb[2] = __hfma2(h2bc(tvb.z), h2bc(yvb.z), pb[2]);
        pb[3] = __hfma2(h2bc(tvb.w), h2bc(yvb.w), pb[3]);
        if((t & 3) == 3){                     // flush fp16 accumulators (chain <= 4)
            #pragma unroll
            for(int c2 = 0; c2 < 4; c2++){
                float2 ua = __half22float2(pa[c2]);
                float2 ub = __half22float2(pb[c2]);
                ca[2*c2]   += ua.x; ca[2*c2+1] += ua.y;
                cb[2*c2]   += ub.x; cb[2*c2+1] += ub.y;
                pa[c2] = hz; pb[c2] = hz;
            }
        }
    }
    #pragma unroll
    for(int c2 = 0; c2 < 4; c2++){            // final flush (remainder)
        float2 ua = __half22float2(pa[c2]);
        float2 ub = __half22float2(pb[c2]);
        ca[2*c2]   += ua.x; ca[2*c2+1] += ua.y;
        cb[2*c2]   += ub.x; cb[2*c2+1] += ub.y;
    }
    #pragma unroll
    for(int i = 0; i < 8; i++){
        ca[i] += __shfl_xor(ca[i], 16);
        ca[i] += __shfl_xor(ca[i], 32);
        cb[i] += __shfl_xor(cb[i], 16);
        cb[i] += __shfl_xor(cb[i], 32);
    }
    if(qf == 0){
        unsigned w0 = (unsigned short)bf16r(ca[0]) | ((unsigned)(unsigned short)bf16r(ca[1]) << 16);
        unsigned w1 = (unsigned short)bf16r(ca[2]) | ((unsigned)(unsigned short)bf16r(ca[3]) << 16);
        unsigned w2 = (unsigned short)bf16r(ca[4]) | ((unsigned)(unsigned short)bf16r(ca[5]) << 16);
        unsigned w3 = (unsigned short)bf16r(ca[6]) | ((unsigned)(unsigned short)bf16r(ca[7]) << 16);
        uint2 u01 = {w0, w1}, u23 = {w2, w3};
        *(uint2*)&s_a[a0*STR + f8]     = u01;
        *(uint2*)&s_a[a0*STR + f8 + 4] = u23;
        unsigned v0 = (unsigned short)bf16r(cb[0]) | ((unsigned)(unsigned short)bf16r(cb[1]) << 16);
        unsigned v1 = (unsigned short)bf16r(cb[2]) | ((unsigned)(unsigned short)bf16r(cb[3]) << 16);
        unsigned v2 = (unsigned short)bf16r(cb[4]) | ((unsigned)(unsigned short)bf16r(cb[5]) << 16);
        unsigned v3 = (unsigned short)bf16r(cb[6]) | ((unsigned)(unsigned short)bf16r(cb[7]) << 16);
        uint2 s01 = {v0, v1}, s23 = {v2, v3};
        *(uint2*)&s_a[a1*STR + f8]     = s01;
        *(uint2*)&s_a[a1*STR + f8 + 4] = s23;
    }

    // ---- residual x read: deferred (hides under GEMM1 weight fetch) ----
    unsigned long long xo = (unsigned long long)x;
    asm volatile("" : "+s"(xo));
    float xra[4], xrb[4];
    if(q < 2){
        const float* xro = (const float*)xo;
        #pragma unroll
        for(int j = 0; j < 4; j++){
            xra[j] = xro[(row0 + 4*q + j)*FF + col];
            xrb[j] = xro[(row0 + 4*q + j)*FF + col2];
        }
    }

    // ---- GEMM1 weights for both col-tiles (opaque ptr, loaded here) ----
    unsigned long long w1o = (unsigned long long)w1p;
    asm volatile("" : "+s"(w1o));
    bf16x8 wfa[4], wfa2[4];
    {
        const bf16x8* w1v = (const bf16x8*)w1o;
        #pragma unroll
        for(int ks = 0; ks < 4; ks++){
            wfa[ks]  = w1v[(ks*8 + wv)*64 + lane];
            wfa2[ks] = w1v[(ks*8 + wv + 4)*64 + lane];
        }
    }
    __syncthreads();

    // ---- GEMM1: t = ssp(agg @ f2w + f2b), both col-tiles ----
    f32x4 acc0 = {b1a, b1a, b1a, b1a};
    f32x4 acc1 = {b1b, b1b, b1b, b1b};
    #pragma unroll
    for(int ks = 0; ks < 4; ks++){
        const short* ap = s_a + m*STR + 32*ks + 8*q;
        bf16x4 lo = *(const bf16x4*)ap;
        bf16x4 hi = *(const bf16x4*)(ap + 4);
        bf16x8 af;
        af[0]=lo[0]; af[1]=lo[1]; af[2]=lo[2]; af[3]=lo[3];
        af[4]=hi[0]; af[5]=hi[1]; af[6]=hi[2]; af[7]=hi[3];
        acc0 = __builtin_amdgcn_mfma_f32_16x16x32_bf16(af, wfa[ks],  acc0, 0, 0, 0);
        acc1 = __builtin_amdgcn_mfma_f32_16x16x32_bf16(af, wfa2[ks], acc1, 0, 0, 0);
    }

    // ---- GEMM2 weights: fresh sets ----
    unsigned long long w2o = (unsigned long long)w2p;
    asm volatile("" : "+s"(w2o));
    bf16x8 wfb[4], wfb2[4];
    {
        const bf16x8* w2v = (const bf16x8*)w2o;
        #pragma unroll
        for(int ks = 0; ks < 4; ks++){
            wfb[ks]  = w2v[(ks*8 + wv)*64 + lane];
            wfb2[ks] = w2v[(ks*8 + wv + 4)*64 + lane];
        }
    }

    #pragma unroll
    for(int j = 0; j < 4; j++){
        s_t[(4*q + j)*STR + col]  = bf16r(sspf(acc0[j]));
        s_t[(4*q + j)*STR + col2] = bf16r(sspf(acc1[j]));
    }
    __syncthreads();

    // ---- GEMM2: v = t @ dw + db ; xnew = x + v ----
    f32x4 a20 = {b2a, b2a, b2a, b2a};
    f32x4 a21 = {b2b, b2b, b2b, b2b};
    #pragma unroll
    for(int ks = 0; ks < 4; ks++){
        const short* ap = s_t + m*STR + 32*ks + 8*q;
        bf16x4 lo = *(const bf16x4*)ap;
        bf16x4 hi = *(const bf16x4*)(ap + 4);
        bf16x8 af;
        af[0]=lo[0]; af[1]=lo[1]; af[2]=lo[2]; af[3]=lo[3];
        af[4]=hi[0]; af[5]=hi[1]; af[6]=hi[2]; af[7]=hi[3];
        a20 = __builtin_amdgcn_mfma_f32_16x16x32_bf16(af, wfb[ks],  a20, 0, 0, 0);
        a21 = __builtin_amdgcn_mfma_f32_16x16x32_bf16(af, wfb2[ks], a21, 0, 0, 0);
    }

    float xna[4], xnb[4];
    if(q < 2){
        #pragma unroll
        for(int j = 0; j < 4; j++){
            xna[j] = xra[j] + a20[j];
            xnb[j] = xrb[j] + a21[j];
            x[(row0 + 4*q + j)*FF + col]  = xna[j];
            x[(row0 + 4*q + j)*FF + col2] = xnb[j];
        }
    }
    if(w3p){
        // ---- GEMM3 weights: fresh sets ----
        unsigned long long w3o = (unsigned long long)w3p;
        asm volatile("" : "+s"(w3o));
        bf16x8 wfc[4], wfc2[4];
        {
            const bf16x8* w3v = (const bf16x8*)w3o;
            #pragma unroll
            for(int ks = 0; ks < 4; ks++){
                wfc[ks]  = w3v[(ks*8 + wv)*64 + lane];
                wfc2[ks] = w3v[(ks*8 + wv + 4)*64 + lane];
            }
        }
        // s_a rows 0-7 <- xnew (rows 8-15 stale junk, only affect discarded D rows)
        if(q < 2){
            #pragma unroll
            for(int j = 0; j < 4; j++){
                s_a[(4*q + j)*STR + col]  = bf16r(xna[j]);
                s_a[(4*q + j)*STR + col2] = bf16r(xnb[j]);
            }
        }
        __syncthreads();
        // ---- GEMM3: ynext = xnew @ in2f_next (fp16 out) ----
        f32x4 a30 = {0.f, 0.f, 0.f, 0.f};
        f32x4 a31 = {0.f, 0.f, 0.f, 0.f};
        #pragma unroll
        for(int ks = 0; ks < 4; ks++){
            const short* ap = s_a + m*STR + 32*ks + 8*q;
            bf16x4 lo = *(const bf16x4*)ap;
            bf16x4 hi = *(const bf16x4*)(ap + 4);
            bf16x8 af;
            af[0]=lo[0]; af[1]=lo[1]; af[2]=lo[2]; af[3]=lo[3];
            af[4]=hi[0]; af[5]=hi[1]; af[6]=hi[2]; af[7]=hi[3];
            a30 = __builtin_amdgcn_mfma_f32_16x16x32_bf16(af, wfc[ks],  a30, 0, 0, 0);
            a31 = __builtin_amdgcn_mfma_f32_16x16x32_bf16(af, wfc2[ks], a31, 0, 0, 0);
        }
        if(q < 2){
            #pragma unroll
            for(int j = 0; j < 4; j++){
                ynext[(row0 + 4*q + j)*FF + col]  = __float2half(a30[j]);
                ynext[(row0 + 4*q + j)*FF + col2] = __float2half(a31[j]);
            }
        }
    }
}

extern "C" void kernel_launch(void* const* d_in, const int* in_sizes, int n_in,
                              void* d_out, int out_size, void* d_ws, size_t ws_size,
                              hipStream_t stream) {
    const int*   zat  = (const int*)  d_in[0];
    const float* pos  = (const float*)d_in[1];
    const float* cell = (const float*)d_in[2];
    const float* coff = (const float*)d_in[3];
    const int*   nbr  = (const int*)  d_in[4];
    const float* mask = (const float*)d_in[5];
    const float* emb  = (const float*)d_in[6];
    const float* fw1  = (const float*)d_in[7];
    const float* fb1  = (const float*)d_in[8];
    const float* fw2  = (const float*)d_in[9];
    const float* fb2  = (const float*)d_in[10];
    const float* in2f = (const float*)d_in[11];
    const float* f2w  = (const float*)d_in[12];
    const float* f2b  = (const float*)d_in[13];
    const float* dw   = (const float*)d_in[14];
    const float* db   = (const float*)d_in[15];

    float* x = (float*)d_out;                      // x lives in d_out
    unsigned* codes = (unsigned*)d_ws;             // B*A*N u32         (2 MB)
    __half* Tb = (__half*)(codes + BB*AA*NN);      // 3*KT*FF half      (768 KB)
    __half* yA = Tb + 3*KT*FF;                     // B*A*F half        (2 MB)
    __half* yB = yA + BB*AA*FF;                    // B*A*F half        (2 MB)
    short*  Wp = (short*)(yB + BB*AA*FF);          // 8*16384 bf16      (256 KB)
    int*    cnt = (int*)(Wp + 8*16384);            // B*A int           (32 KB)

    k_prep<<<960, 512, 0, stream>>>(pos, cell, coff, nbr, mask, zat, emb,
                                    fw1, fb1, fw2, fb2, in2f, f2w, dw,
                                    codes, cnt, Wp, Tb, x, yA);

    k_layerM<<<BB*AA/8, 256, 0, stream>>>(codes, cnt, Tb,           yA,
                                          Wp + 0*16384, f2b,        Wp + 3*16384, db,
                                          Wp + 6*16384, x, yB);
    k_layerM<<<BB*AA/8, 256, 0, stream>>>(codes, cnt, Tb + KT*FF,   yB,
                                          Wp + 1*16384, f2b + FF,   Wp + 4*16384, db + FF,
                                          Wp + 7*16384, x, yA);
    k_layerM<<<BB*AA/8, 256, 0, stream>>>(codes, cnt, Tb + 2*KT*FF, yA,
                                          Wp + 2*16384, f2b + 2*FF, Wp + 5*16384, db + 2*FF,
                                          nullptr, x, nullptr);
}

// Round 15
// 51.918 us; speedup vs baseline: 1.2613x; 1.2613x over previous
//
#include <hip/hip_runtime.h>
#include <hip/hip_fp16.h>
#include <math.h>

#define BB 8
#define AA 1024
#define NN 64
#define FF 128
#define NG 25

#define WIDTH 0.2083333333f     /* 5/24 */
#define COEF  (-0.5f/(WIDTH*WIDTH))
#define PI_F  3.14159265358979f
#define CUTOFF 5.0f

#define KT 1024
#define HT (CUTOFF/(KT-1))
#define INVH ((float)(KT-1)/CUTOFF)
#define SENT ((unsigned)(KT-1))   /* sentinel code: T row = 0, j = 0 */

#define STR 132   /* LDS bf16 row stride (264 B) — verified conflict-free */

typedef __attribute__((ext_vector_type(8))) short bf16x8;
typedef __attribute__((ext_vector_type(4))) short bf16x4;
typedef __attribute__((ext_vector_type(4))) float f32x4;

__device__ __forceinline__ float sspf(float x){
    return fmaxf(x, 0.f) + log1pf(expf(-fabsf(x))) - 0.69314718056f;
}
__device__ __forceinline__ short bf16r(float x){
    union { float f; unsigned u; } v; v.f = x;
    unsigned r = v.u + 0x7FFF + ((v.u >> 16) & 1);
    return (short)(r >> 16);
}
__device__ __forceinline__ __half2 h2bc(unsigned u){
    union { unsigned u; __half2 h; } v; v.u = u; return v.h;
}

// ==== single prolog (round-13 proven, unchanged): codes+embed/in2f0
// (blocks 0..511), filter table (512..703), weight packing (704..959).
__global__ __launch_bounds__(512) void k_prep(const float* __restrict__ pos,
                        const float* __restrict__ cell,
                        const float* __restrict__ coff, const int* __restrict__ nbr,
                        const float* __restrict__ mask,
                        const int* __restrict__ z, const float* __restrict__ emb,
                        const float* __restrict__ fw1, const float* __restrict__ fb1,
                        const float* __restrict__ fw2, const float* __restrict__ fb2,
                        const float* __restrict__ in2f, const float* __restrict__ f2w,
                        const float* __restrict__ dw,
                        unsigned* __restrict__ codes, int* __restrict__ cnt,
                        short* __restrict__ Wp,
                        __half* __restrict__ T, float* __restrict__ x,
                        __half* __restrict__ y){
    __shared__ __align__(16) char smem[NG*FF*4 + 16*28*4 + 16*STR*2];
    float* s_w1 = (float*)smem;                              // NG*FF
    float* s_g  = (float*)(smem + NG*FF*4);                  // 16*28
    short* s_a  = (short*)(smem + NG*FF*4 + 16*28*4);        // 16*STR
    __shared__ unsigned s_codeP[16*NN];
    __shared__ int s_cnt[16];

    int p = blockIdx.x;
    int tid = threadIdx.x, wv = tid >> 6, lane = tid & 63;
    int m = lane & 15, q = lane >> 4;
    int col = 16*wv + m;

    if(p < 512){
        // ---- FIRST + CODES: 16 atoms, XCD-swizzled (batch = p&7) ----
        int row0 = ((p & 7)*64 + (p >> 3))*16;
        if(tid < 16) s_cnt[tid] = 0;
        s_codeP[2*tid]   = SENT;             // sentinel-fill all 1024 slots
        s_codeP[2*tid+1] = SENT;
        __syncthreads();
        #pragma unroll
        for(int u = 0; u < 2; u++){
            int pr = 2*tid + u;              // 0..1023
            int rr = pr >> 6, n = pr & 63;
            int row = row0 + rr;             // b*A + a
            int b = row >> 10;
            int flat = row*NN + n;
            int j = nbr[flat];
            const float* pi = pos + (size_t)row*3;
            const float* pj = pos + (size_t)(b*AA + j)*3;
            const float* co = coff + (size_t)flat*3;
            const float* cl = cell + b*9;
            float ox = co[0]*cl[0] + co[1]*cl[3] + co[2]*cl[6];
            float oy = co[0]*cl[1] + co[1]*cl[4] + co[2]*cl[7];
            float oz = co[0]*cl[2] + co[1]*cl[5] + co[2]*cl[8];
            float vx = pj[0]-pi[0]+ox, vy = pj[1]-pi[1]+oy, vz = pj[2]-pi[2]+oz;
            float d2 = vx*vx + vy*vy + vz*vz;
            float mk = mask[flat];
            float r  = sqrtf(mk > 0.f ? d2 : 1.0f) * mk;
            if(mk > 0.f && r < CUTOFF){      // out-of-cutoff pairs contribute 0: skip
                int iv = (int)(r*INVH + 0.5f);
                if(iv > KT-1) iv = KT-1;
                int ps = atomicAdd(&s_cnt[rr], 1);
                s_codeP[rr*NN + ps] = (unsigned)iv | ((unsigned)j << 16);
            }
        }
        __syncthreads();
        *(uint2*)&codes[row0*NN + 2*tid] = *(uint2*)&s_codeP[2*tid];
        if(tid < 16) cnt[row0 + tid] = s_cnt[tid];

        // self-pack in2f[0] fragments from fp32
        bf16x8 wf[4];
        #pragma unroll
        for(int ks = 0; ks < 4; ks++)
            #pragma unroll
            for(int i = 0; i < 8; i++)
                wf[ks][i] = bf16r(in2f[(32*ks + 8*q + i)*FF + col]);
        for(int i = tid; i < 16*FF; i += 512){
            int rr = i >> 7, f = i & (FF-1);
            float v = emb[z[row0+rr]*FF + f];
            x[(row0+rr)*FF + f] = v;
            s_a[rr*STR + f] = bf16r(v);
        }
        __syncthreads();
        f32x4 acc = {0.f,0.f,0.f,0.f};
        #pragma unroll
        for(int ks = 0; ks < 4; ks++){
            const short* ap = s_a + m*STR + 32*ks + 8*q;
            bf16x4 lo = *(const bf16x4*)ap;
            bf16x4 hi = *(const bf16x4*)(ap + 4);
            bf16x8 af;
            af[0]=lo[0]; af[1]=lo[1]; af[2]=lo[2]; af[3]=lo[3];
            af[4]=hi[0]; af[5]=hi[1]; af[6]=hi[2]; af[7]=hi[3];
            acc = __builtin_amdgcn_mfma_f32_16x16x32_bf16(af, wf[ks], acc, 0, 0, 0);
        }
        #pragma unroll
        for(int j = 0; j < 4; j++)
            y[(row0 + 4*q + j)*FF + col] = __float2half(acc[j]);
    } else if(p < 704){
        // ---- TABLE: knots 16*kb..16*kb+15 of layer l (64 blocks/layer) ----
        int tb = p - 512;
        int l = tb >> 6;
        int kb = tb & 63;
        const float* w2s = fw2 + l*16384;
        bf16x8 wf[4];
        #pragma unroll
        for(int ks = 0; ks < 4; ks++)
            #pragma unroll
            for(int i = 0; i < 8; i++)
                wf[ks][i] = bf16r(w2s[(32*ks + 8*q + i)*FF + col]);

        for(int i = tid; i < NG*FF; i += 512) s_w1[i] = fw1[l*NG*FF + i];
        for(int i = tid; i < 16*NG; i += 512){
            int kn = i/25, g = i - 25*kn;
            float d = (16*kb + kn)*HT - g*WIDTH;
            s_g[kn*28 + g] = expf(COEF*d*d);
        }
        __syncthreads();
        {
            int f = tid & (FF-1), g4 = tid >> 7;
            float b1v = fb1[l*FF + f];
            #pragma unroll
            for(int i = 0; i < 4; i++){
                int kn = g4 + 4*i;
                float zz = b1v;
                for(int g = 0; g < NG; g++)
                    zz = fmaf(s_g[kn*28 + g], s_w1[g*FF + f], zz);
                s_a[kn*STR + f] = bf16r(sspf(zz));
            }
        }
        __syncthreads();
        float b2 = fb2[l*FF + col];
        f32x4 acc = {b2, b2, b2, b2};
        #pragma unroll
        for(int ks = 0; ks < 4; ks++){
            const short* ap = s_a + m*STR + 32*ks + 8*q;
            bf16x4 lo = *(const bf16x4*)ap;
            bf16x4 hi = *(const bf16x4*)(ap + 4);
            bf16x8 af;
            af[0]=lo[0]; af[1]=lo[1]; af[2]=lo[2]; af[3]=lo[3];
            af[4]=hi[0]; af[5]=hi[1]; af[6]=hi[2]; af[7]=hi[3];
            acc = __builtin_amdgcn_mfma_f32_16x16x32_bf16(af, wf[ks], acc, 0, 0, 0);
        }
        #pragma unroll
        for(int j = 0; j < 4; j++){
            int kn = 16*kb + 4*q + j;
            float r = kn*HT;
            float C = (r < CUTOFF) ? 0.5f*(cosf(r*(PI_F/CUTOFF)) + 1.0f) : 0.f;
            T[(l*KT + kn)*FF + col] = __float2half(acc[j]*C);
        }
    } else {
        // ---- PACK: ids 0..2 f2w[l]; 3..5 dw[l]; 6,7 in2f[1],in2f[2] ----
        int idx = (p - 704)*512 + tid;               // < 8*16384
        int id = idx >> 14, rem = idx & 16383;
        int ks = rem >> 12, nt = (rem >> 9) & 7, ln = (rem >> 3) & 63, i = rem & 7;
        int k = 32*ks + 8*(ln >> 4) + i;
        int f = 16*nt + (ln & 15);
        const float* src = (id < 3) ? f2w + id*16384
                         : (id < 6) ? dw  + (id-3)*16384
                                    : in2f + (id-5)*16384;
        Wp[idx] = bf16r(src[k*FF + f]);
    }
}

// ---- fused layer (round-13 body; wave-local code staging, one fewer barrier) ----
__global__ __launch_bounds__(512) void k_layerM(const unsigned* __restrict__ codes,
                                                const int* __restrict__ cnt,
                                                const __half* __restrict__ Tl,
                                                const __half* __restrict__ yin,
                                                const short* __restrict__ w1p,
                                                const float* __restrict__ f2b,
                                                const short* __restrict__ w2p,
                                                const float* __restrict__ db,
                                                const short* __restrict__ w3p,
                                                float* __restrict__ x,
                                                __half* __restrict__ ynext){
    __shared__ unsigned s_code[16*NN];
    __shared__ short s_a[16*STR];
    __shared__ short s_t[16*STR];

    int tid = threadIdx.x, wv = tid >> 6, lane = tid & 63;
    int m = lane & 15, q = lane >> 4;
    int p = blockIdx.x;
    int b = p & 7;
    int row0 = (b*64 + (p >> 3))*16;
    int col = 16*wv + m;

    float bias1 = f2b[col], bias2 = db[col];

    // ---- wave-local code staging: wave wv loads atoms 2wv,2wv+1's codes into
    // the stripe only it reads -> same-wave LDS dependency, no barrier (r2 idiom)
    int a0 = 2*wv, a1 = 2*wv + 1;
    *(uint2*)&s_code[a0*NN + 2*lane] =
        *(const uint2*)&codes[(row0 + a0)*NN + 2*lane];

    // ---- conv: branchless (sentinel-padded lists); quarter-wave = 1 neighbor ----
    int qf = lane >> 4, fl = lane & 15, f8 = 8*fl;
    const __half* yb = yin + ((size_t)b*AA << 7) + f8;
    const __half* tb = Tl + f8;
    int c0 = cnt[row0 + a0], c1 = cnt[row0 + a1];
    int cm = c0 > c1 ? c0 : c1;
    int nmax = (cm + 3) >> 2;                // wave-uniform
    __half2 hz = __float2half2_rn(0.f);
    __half2 pa[4] = {hz,hz,hz,hz}, pb[4] = {hz,hz,hz,hz};
    float ca[8] = {0,0,0,0,0,0,0,0}, cb[8] = {0,0,0,0,0,0,0,0};
    #pragma unroll 4
    for(int t = 0; t < nmax; t++){
        unsigned cda = s_code[a0*NN + 4*t + qf];
        unsigned cdb = s_code[a1*NN + 4*t + qf];
        uint4 tva = *(const uint4*)(tb + ((cda & 0xFFFFu) << 7));
        uint4 yva = *(const uint4*)(yb + ((size_t)(cda >> 16) << 7));
        uint4 tvb = *(const uint4*)(tb + ((cdb & 0xFFFFu) << 7));
        uint4 yvb = *(const uint4*)(yb + ((size_t)(cdb >> 16) << 7));
        pa[0] = __hfma2(h2bc(tva.x), h2bc(yva.x), pa[0]);
        pa[1] = __hfma2(h2bc(tva.y), h2bc(yva.y), pa[1]);
        pa[2] = __hfma2(h2bc(tva.z), h2bc(yva.z), pa[2]);
        pa[3] = __hfma2(h2bc(tva.w), h2bc(yva.w), pa[3]);
        pb[0] = __hfma2(h2bc(tvb.x), h2bc(yvb.x), pb[0]);
        pb[1] = __hfma2(h2bc(tvb.y), h2bc(yvb.y), pb[1]);
        pb[2] = __hfma2(h2bc(tvb.z), h2bc(yvb.z), pb[2]);
        pb[3] = __hfma2(h2bc(tvb.w), h2bc(yvb.w), pb[3]);
        if((t & 3) == 3){                    // flush fp16 accumulators (chain <= 4)
            #pragma unroll
            for(int c2 = 0; c2 < 4; c2++){
                float2 ua = __half22float2(pa[c2]);
                float2 ub = __half22float2(pb[c2]);
                ca[2*c2]   += ua.x; ca[2*c2+1] += ua.y;
                cb[2*c2]   += ub.x; cb[2*c2+1] += ub.y;
                pa[c2] = hz; pb[c2] = hz;
            }
        }
    }
    #pragma unroll
    for(int c2 = 0; c2 < 4; c2++){           // final flush (remainder)
        float2 ua = __half22float2(pa[c2]);
        float2 ub = __half22float2(pb[c2]);
        ca[2*c2]   += ua.x; ca[2*c2+1] += ua.y;
        cb[2*c2]   += ub.x; cb[2*c2+1] += ub.y;
    }
    #pragma unroll
    for(int i = 0; i < 8; i++){
        ca[i] += __shfl_xor(ca[i], 16);
        ca[i] += __shfl_xor(ca[i], 32);
        cb[i] += __shfl_xor(cb[i], 16);
        cb[i] += __shfl_xor(cb[i], 32);
    }
    if(qf == 0){
        unsigned w0 = (unsigned short)bf16r(ca[0]) | ((unsigned)(unsigned short)bf16r(ca[1]) << 16);
        unsigned w1 = (unsigned short)bf16r(ca[2]) | ((unsigned)(unsigned short)bf16r(ca[3]) << 16);
        unsigned w2 = (unsigned short)bf16r(ca[4]) | ((unsigned)(unsigned short)bf16r(ca[5]) << 16);
        unsigned w3 = (unsigned short)bf16r(ca[6]) | ((unsigned)(unsigned short)bf16r(ca[7]) << 16);
        uint2 u01 = {w0, w1}, u23 = {w2, w3};
        *(uint2*)&s_a[a0*STR + f8]     = u01;
        *(uint2*)&s_a[a0*STR + f8 + 4] = u23;
        unsigned v0 = (unsigned short)bf16r(cb[0]) | ((unsigned)(unsigned short)bf16r(cb[1]) << 16);
        unsigned v1 = (unsigned short)bf16r(cb[2]) | ((unsigned)(unsigned short)bf16r(cb[3]) << 16);
        unsigned v2 = (unsigned short)bf16r(cb[4]) | ((unsigned)(unsigned short)bf16r(cb[5]) << 16);
        unsigned v3 = (unsigned short)bf16r(cb[6]) | ((unsigned)(unsigned short)bf16r(cb[7]) << 16);
        uint2 s01 = {v0, v1}, s23 = {v2, v3};
        *(uint2*)&s_a[a1*STR + f8]     = s01;
        *(uint2*)&s_a[a1*STR + f8 + 4] = s23;
    }

    // ---- residual x read: deferred to here (hides under GEMM1 weight fetch) ----
    unsigned long long xo = (unsigned long long)x;
    asm volatile("" : "+s"(xo));
    float xr[4];
    {
        const float* xro = (const float*)xo;
        #pragma unroll
        for(int j = 0; j < 4; j++) xr[j] = xro[(row0 + 4*q + j)*FF + col];
    }

    // ---- GEMM1 weights: loaded HERE via opaque pointer (r9 proven idiom) ----
    unsigned long long w1o = (unsigned long long)w1p;
    asm volatile("" : "+s"(w1o));
    bf16x8 wfa[4];
    {
        const bf16x8* w1v = (const bf16x8*)w1o;
        #pragma unroll
        for(int ks = 0; ks < 4; ks++) wfa[ks] = w1v[(ks*8 + wv)*64 + lane];
    }
    __syncthreads();

    // ---- GEMM1: t = ssp(agg @ f2w + f2b) ----
    f32x4 acc = {bias1, bias1, bias1, bias1};
    #pragma unroll
    for(int ks = 0; ks < 4; ks++){
        const short* ap = s_a + m*STR + 32*ks + 8*q;
        bf16x4 lo = *(const bf16x4*)ap;
        bf16x4 hi = *(const bf16x4*)(ap + 4);
        bf16x8 af;
        af[0]=lo[0]; af[1]=lo[1]; af[2]=lo[2]; af[3]=lo[3];
        af[4]=hi[0]; af[5]=hi[1]; af[6]=hi[2]; af[7]=hi[3];
        acc = __builtin_amdgcn_mfma_f32_16x16x32_bf16(af, wfa[ks], acc, 0, 0, 0);
    }

    // ---- GEMM2 weights: fresh set, loaded after GEMM1 ----
    unsigned long long w2o = (unsigned long long)w2p;
    asm volatile("" : "+s"(w2o));
    bf16x8 wfb[4];
    {
        const bf16x8* w2v = (const bf16x8*)w2o;
        #pragma unroll
        for(int ks = 0; ks < 4; ks++) wfb[ks] = w2v[(ks*8 + wv)*64 + lane];
    }

    #pragma unroll
    for(int j = 0; j < 4; j++)
        s_t[(4*q + j)*STR + col] = bf16r(sspf(acc[j]));
    __syncthreads();

    // ---- GEMM2: v = t @ dw + db ; xnew = x + v ----
    f32x4 a2 = {bias2, bias2, bias2, bias2};
    #pragma unroll
    for(int ks = 0; ks < 4; ks++){
        const short* ap = s_t + m*STR + 32*ks + 8*q;
        bf16x4 lo = *(const bf16x4*)ap;
        bf16x4 hi = *(const bf16x4*)(ap + 4);
        bf16x8 af;
        af[0]=lo[0]; af[1]=lo[1]; af[2]=lo[2]; af[3]=lo[3];
        af[4]=hi[0]; af[5]=hi[1]; af[6]=hi[2]; af[7]=hi[3];
        a2 = __builtin_amdgcn_mfma_f32_16x16x32_bf16(af, wfb[ks], a2, 0, 0, 0);
    }

    float xn[4];
    #pragma unroll
    for(int j = 0; j < 4; j++){
        xn[j] = xr[j] + a2[j];
        x[(row0 + 4*q + j)*FF + col] = xn[j];
    }
    if(w3p){
        // ---- GEMM3 weights: fresh set ----
        unsigned long long w3o = (unsigned long long)w3p;
        asm volatile("" : "+s"(w3o));
        bf16x8 wfc[4];
        {
            const bf16x8* w3v = (const bf16x8*)w3o;
            #pragma unroll
            for(int ks = 0; ks < 4; ks++) wfc[ks] = w3v[(ks*8 + wv)*64 + lane];
        }
        // s_a's last reader was GEMM1 (pre-barrier) -> safe to overwrite now
        #pragma unroll
        for(int j = 0; j < 4; j++)
            s_a[(4*q + j)*STR + col] = bf16r(xn[j]);
        __syncthreads();
        // ---- GEMM3: ynext = xnew @ in2f_next (fp16 out) ----
        f32x4 a3 = {0.f, 0.f, 0.f, 0.f};
        #pragma unroll
        for(int ks = 0; ks < 4; ks++){
            const short* ap = s_a + m*STR + 32*ks + 8*q;
            bf16x4 lo = *(const bf16x4*)ap;
            bf16x4 hi = *(const bf16x4*)(ap + 4);
            bf16x8 af;
            af[0]=lo[0]; af[1]=lo[1]; af[2]=lo[2]; af[3]=lo[3];
            af[4]=hi[0]; af[5]=hi[1]; af[6]=hi[2]; af[7]=hi[3];
            a3 = __builtin_amdgcn_mfma_f32_16x16x32_bf16(af, wfc[ks], a3, 0, 0, 0);
        }
        #pragma unroll
        for(int j = 0; j < 4; j++)
            ynext[(row0 + 4*q + j)*FF + col] = __float2half(a3[j]);
    }
}

extern "C" void kernel_launch(void* const* d_in, const int* in_sizes, int n_in,
                              void* d_out, int out_size, void* d_ws, size_t ws_size,
                              hipStream_t stream) {
    const int*   zat  = (const int*)  d_in[0];
    const float* pos  = (const float*)d_in[1];
    const float* cell = (const float*)d_in[2];
    const float* coff = (const float*)d_in[3];
    const int*   nbr  = (const int*)  d_in[4];
    const float* mask = (const float*)d_in[5];
    const float* emb  = (const float*)d_in[6];
    const float* fw1  = (const float*)d_in[7];
    const float* fb1  = (const float*)d_in[8];
    const float* fw2  = (const float*)d_in[9];
    const float* fb2  = (const float*)d_in[10];
    const float* in2f = (const float*)d_in[11];
    const float* f2w  = (const float*)d_in[12];
    const float* f2b  = (const float*)d_in[13];
    const float* dw   = (const float*)d_in[14];
    const float* db   = (const float*)d_in[15];

    float* x = (float*)d_out;                      // x lives in d_out
    unsigned* codes = (unsigned*)d_ws;             // B*A*N u32         (2 MB)
    __half* Tb = (__half*)(codes + BB*AA*NN);      // 3*KT*FF half      (768 KB)
    __half* yA = Tb + 3*KT*FF;                     // B*A*F half        (2 MB)
    __half* yB = yA + BB*AA*FF;                    // B*A*F half        (2 MB)
    short*  Wp = (short*)(yB + BB*AA*FF);          // 8*16384 bf16      (256 KB)
    int*    cnt = (int*)(Wp + 8*16384);            // B*A int           (32 KB)

    k_prep<<<960, 512, 0, stream>>>(pos, cell, coff, nbr, mask, zat, emb,
                                    fw1, fb1, fw2, fb2, in2f, f2w, dw,
                                    codes, cnt, Wp, Tb, x, yA);

    k_layerM<<<BB*AA/16, 512, 0, stream>>>(codes, cnt, Tb,           yA,
                                           Wp + 0*16384, f2b,        Wp + 3*16384, db,
                                           Wp + 6*16384, x, yB);
    k_layerM<<<BB*AA/16, 512, 0, stream>>>(codes, cnt, Tb + KT*FF,   yB,
                                           Wp + 1*16384, f2b + FF,   Wp + 4*16384, db + FF,
                                           Wp + 7*16384, x, yA);
    k_layerM<<<BB*AA/16, 512, 0, stream>>>(codes, cnt, Tb + 2*KT*FF, yA,
                                           Wp + 2*16384, f2b + 2*FF, Wp + 5*16384, db + 2*FF,
                                           nullptr, x, nullptr);
}